// Round 13
// baseline (253.236 us; speedup 1.0000x reference)
//
#include <hip/hip_runtime.h>
#include <hip/hip_bf16.h>
#include <cstddef>
#include <cstdint>

// MultiHeadAttention: B=2, S=4096, D=512, H=8, HD=64
// Round 13: R12 with P redistribution reverted to the R9/R10-verified
// __shfl_xor(.,32) pattern. permlane32_swap is now RESTRICTED (by three failed
// rounds of evidence) to symmetric reductions only. Mask stays folded into the
// QK^T MFMA C-operand (cbias) — semantically equivalent to R10's pre-max blend.

#define S_LEN 4096
#define DMODEL 512
#define NHEAD 8
#define HDIM 64
#define NWORDS (S_LEN / 64)

typedef __bf16 bf16x8 __attribute__((ext_vector_type(8)));
typedef _Float16 f16x8 __attribute__((ext_vector_type(8)));
typedef float f32x4 __attribute__((ext_vector_type(4)));
typedef float f32x16 __attribute__((ext_vector_type(16)));
typedef int i32x2 __attribute__((ext_vector_type(2)));
typedef unsigned int u32x4 __attribute__((ext_vector_type(4)));
typedef unsigned short u16x4 __attribute__((ext_vector_type(4)));
typedef unsigned short u16x8 __attribute__((ext_vector_type(8)));

__device__ __forceinline__ unsigned short f2bf(float x) {
  return __builtin_bit_cast(unsigned short, (__bf16)x);
}
__device__ __forceinline__ float bf2f(unsigned short h) {
  union { unsigned u; float f; } v; v.u = ((unsigned)h) << 16; return v.f;
}
__device__ __forceinline__ float fast_exp2(float x) {
#if __has_builtin(__builtin_amdgcn_exp2f)
  return __builtin_amdgcn_exp2f(x);
#else
  return __expf(x * 0.69314718056f);
#endif
}
__device__ __forceinline__ float max3f(float a, float b, float c) {
  return fmaxf(fmaxf(a, b), c);
}
__device__ __forceinline__ int bit_mask(unsigned hs, int bs) {
#if __has_builtin(__builtin_amdgcn_sbfe)
  return __builtin_amdgcn_sbfe((int)hs, bs, 1);
#else
  return ((int)(hs << (31 - bs))) >> 31;
#endif
}
// permlane32_swap: SYMMETRIC REDUCTIONS ONLY (direction-insensitive).
// Asymmetric exchanges via this op failed 3x (R7/R8/R12) — use shfl_xor.
__device__ __forceinline__ void pl_swap(int& a, int& b) {
#if __has_builtin(__builtin_amdgcn_permlane32_swap)
  i32x2 r = __builtin_amdgcn_permlane32_swap(a, b, false, false);
  a = r[0]; b = r[1];
#else
  asm volatile("v_permlane32_swap_b32 %0, %1" : "+v"(a), "+v"(b));
#endif
}
__device__ __forceinline__ float xhalf_max(float x) {
  int a = __builtin_bit_cast(int, x), b = a;
  pl_swap(a, b);
  return fmaxf(__builtin_bit_cast(float, a), __builtin_bit_cast(float, b));
}
__device__ __forceinline__ float xhalf_sum(float x) {
  int a = __builtin_bit_cast(int, x), b = a;
  pl_swap(a, b);
  return __builtin_bit_cast(float, a) + __builtin_bit_cast(float, b);
}
// swizzled ushort index into a [*][64] 16-bit tile
__device__ __forceinline__ int swzi(int row, int col) {
  return row * 64 + ((col & 7) | ((((col >> 3) ^ row) & 7) << 3));
}
// async global->LDS, 16B per lane; LDS dest = lds + lane*16B (wave-uniform base)
__device__ __forceinline__ void gload16(const unsigned short* g, unsigned short* lds) {
  __builtin_amdgcn_global_load_lds(
      (const __attribute__((address_space(1))) unsigned int*)g,
      (__attribute__((address_space(3))) unsigned int*)lds, 16, 0, 0);
}

// ---------------------------------------------------------------------------
// fused prep: hi/lo conversions for q,k,v + 4 weights, mask packing. grid (2048,5)
// ---------------------------------------------------------------------------
__global__ __launch_bounds__(256) void prep(
    const float* __restrict__ query, const float* __restrict__ key,
    const float* __restrict__ value,
    const float* __restrict__ w0, const float* __restrict__ w1,
    const float* __restrict__ w2, const float* __restrict__ w3,
    const int* __restrict__ mask,
    unsigned short* __restrict__ qh, unsigned short* __restrict__ ql,
    unsigned short* __restrict__ kh, unsigned short* __restrict__ kl,
    unsigned short* __restrict__ vh, unsigned short* __restrict__ vl,
    unsigned short* __restrict__ wbuf, unsigned long long* __restrict__ bits)
{
  const int task = blockIdx.y;
  const int tid = blockIdx.x * 256 + threadIdx.x;
  const int nthr = gridDim.x * 256;

  if (task < 3) {
    const float* x = (task == 0) ? query : (task == 1) ? key : value;
    unsigned short* h = (task == 0) ? qh : (task == 1) ? kh : vh;
    unsigned short* l = (task == 0) ? ql : (task == 1) ? kl : vl;
    const int n4 = (int)((size_t)2 * S_LEN * DMODEL / 4);
    for (int i = tid; i < n4; i += nthr) {
      float4 f = ((const float4*)x)[i];
      float ff[4] = {f.x, f.y, f.z, f.w};
      u16x4 hh, ll;
      #pragma unroll
      for (int j = 0; j < 4; ++j) {
        unsigned short hb = f2bf(ff[j]);
        hh[j] = hb;
        ll[j] = f2bf(ff[j] - bf2f(hb));
      }
      ((u16x4*)h)[i] = hh;
      ((u16x4*)l)[i] = ll;
    }
  } else if (task == 3) {
    const int per = 65536;
    for (int i = tid; i < 4 * per; i += nthr) {
      int wsel = i >> 16, idx = i & (per - 1);
      const float* src = (wsel == 0) ? w0 : (wsel == 1) ? w1 : (wsel == 2) ? w2 : w3;
      unsigned short* h = wbuf + (size_t)wsel * 2 * 262144;
      unsigned short* l = h + 262144;
      float4 f = ((const float4*)src)[idx];
      float ff[4] = {f.x, f.y, f.z, f.w};
      u16x4 hh, ll;
      #pragma unroll
      for (int j = 0; j < 4; ++j) {
        unsigned short hb = f2bf(ff[j]);
        hh[j] = hb;
        ll[j] = f2bf(ff[j] - bf2f(hb));
      }
      ((u16x4*)h)[idx] = hh;
      ((u16x4*)l)[idx] = ll;
    }
  } else {
    const int nwords = 2 * S_LEN * NWORDS;
    int gw = tid >> 6;
    int lane = threadIdx.x & 63;
    int nw = nthr >> 6;
    for (int w = gw; w < nwords; w += nw) {
      int v = mask[(size_t)w * 64 + lane];
      unsigned long long bm = __ballot(v != 0);
      if (lane == 0) bits[w] = bm;
    }
  }
}

// ---------------------------------------------------------------------------
// Fused Q/K/V projections in one launch. blockIdx.z = mode:
//  0: Q (3-pass hi/lo, out fp16 head-split, *log2e)
//  1: K (3-pass hi/lo, out fp16 head-split)
//  2: V (1-pass, out fp16 transposed [B,H,HD,S])
// ---------------------------------------------------------------------------
__global__ __launch_bounds__(256) void proj_qkv(
    const unsigned short* __restrict__ qxh, const unsigned short* __restrict__ qxl,
    const unsigned short* __restrict__ kxh, const unsigned short* __restrict__ kxl,
    const unsigned short* __restrict__ vxh, const unsigned short* __restrict__ vxl,
    const unsigned short* __restrict__ wbuf,
    const float* __restrict__ bq, const float* __restrict__ bk, const float* __restrict__ bv,
    unsigned short* __restrict__ qout, unsigned short* __restrict__ kout,
    unsigned short* __restrict__ vout)
{
  const int mode = blockIdx.z;
  const bool tri = (mode < 2);
  const unsigned short* xh = (mode == 0) ? qxh : (mode == 1) ? kxh : vxh;
  const unsigned short* xl = (mode == 0) ? qxl : (mode == 1) ? kxl : vxl;
  const unsigned short* wh = wbuf + (size_t)mode * 2 * 262144;
  const unsigned short* wl = wh + 262144;
  const float* bias = (mode == 0) ? bq : (mode == 1) ? bk : bv;
  unsigned short* out = (mode == 0) ? qout : (mode == 1) ? kout : vout;
  const float oscale = (mode == 0) ? 1.44269504f : 1.0f;

  __shared__ __align__(16) unsigned short SMEM[24576];
  unsigned short* Xh = SMEM;
  unsigned short* Xl = SMEM + 8192;
  unsigned short* Wh = SMEM + 16384;
  unsigned short* Wl = SMEM + 20480;

  const int t = threadIdx.x;
  const int lane = t & 63;
  const int w = t >> 6;
  const int c = lane & 15;
  const int g = lane >> 4;
  const int row0 = blockIdx.x * 128;
  const int col0 = blockIdx.y * 64;

  f32x4 acc[2][4];
  #pragma unroll
  for (int mi = 0; mi < 2; ++mi)
    #pragma unroll
    for (int n = 0; n < 4; ++n) acc[mi][n] = (f32x4){0.f, 0.f, 0.f, 0.f};

  u16x8 pxh[4], pxl[4], pwh[2], pwl[2];
  auto issue = [&](int k0) {
    #pragma unroll
    for (int i = 0; i < 4; ++i) {
      int id = i * 256 + t;
      int r = id >> 3, ch = id & 7;
      size_t off = (size_t)(row0 + r) * DMODEL + k0 + ch * 8;
      pxh[i] = *(const u16x8*)(xh + off);
      if (tri) pxl[i] = *(const u16x8*)(xl + off);
    }
    #pragma unroll
    for (int i = 0; i < 2; ++i) {
      int id = i * 256 + t;
      int r = id >> 3, ch = id & 7;
      size_t off = (size_t)(col0 + r) * DMODEL + k0 + ch * 8;
      pwh[i] = *(const u16x8*)(wh + off);
      if (tri) pwl[i] = *(const u16x8*)(wl + off);
    }
  };
  auto commit = [&]() {
    #pragma unroll
    for (int i = 0; i < 4; ++i) {
      int id = i * 256 + t;
      int r = id >> 3, ch = id & 7;
      int dst = r * 64 + (((ch ^ r) & 7) << 3);
      *(u16x8*)&Xh[dst] = pxh[i];
      if (tri) *(u16x8*)&Xl[dst] = pxl[i];
    }
    #pragma unroll
    for (int i = 0; i < 2; ++i) {
      int id = i * 256 + t;
      int r = id >> 3, ch = id & 7;
      int dst = r * 64 + (((ch ^ r) & 7) << 3);
      *(u16x8*)&Wh[dst] = pwh[i];
      if (tri) *(u16x8*)&Wl[dst] = pwl[i];
    }
  };

  issue(0);
  commit();
  __syncthreads();

  for (int k0 = 0; k0 < DMODEL; k0 += 64) {
    const bool more = (k0 + 64) < DMODEL;
    if (more) issue(k0 + 64);

    #pragma unroll
    for (int kk = 0; kk < 2; ++kk) {
      bf16x8 ah[2], al[2], bh_[4], bl_[4];
      #pragma unroll
      for (int mi = 0; mi < 2; ++mi) {
        int r = w * 32 + mi * 16 + c;
        ah[mi] = __builtin_bit_cast(bf16x8, *(const u16x8*)&Xh[swzi(r, (kk * 4 + g) * 8)]);
        if (tri) al[mi] = __builtin_bit_cast(bf16x8, *(const u16x8*)&Xl[swzi(r, (kk * 4 + g) * 8)]);
      }
      #pragma unroll
      for (int n = 0; n < 4; ++n) {
        int r = n * 16 + c;
        bh_[n] = __builtin_bit_cast(bf16x8, *(const u16x8*)&Wh[swzi(r, (kk * 4 + g) * 8)]);
        if (tri) bl_[n] = __builtin_bit_cast(bf16x8, *(const u16x8*)&Wl[swzi(r, (kk * 4 + g) * 8)]);
      }
      #pragma unroll
      for (int mi = 0; mi < 2; ++mi)
        #pragma unroll
        for (int n = 0; n < 4; ++n) {
          acc[mi][n] = __builtin_amdgcn_mfma_f32_16x16x32_bf16(ah[mi], bh_[n], acc[mi][n], 0, 0, 0);
          if (tri) {
            acc[mi][n] = __builtin_amdgcn_mfma_f32_16x16x32_bf16(al[mi], bh_[n], acc[mi][n], 0, 0, 0);
            acc[mi][n] = __builtin_amdgcn_mfma_f32_16x16x32_bf16(ah[mi], bl_[n], acc[mi][n], 0, 0, 0);
          }
        }
    }
    __syncthreads();
    if (more) {
      commit();
      __syncthreads();
    }
  }

  if (mode < 2) {
    #pragma unroll
    for (int mi = 0; mi < 2; ++mi)
      #pragma unroll
      for (int n = 0; n < 4; ++n)
        #pragma unroll
        for (int j = 0; j < 4; ++j) {
          int rr = row0 + w * 32 + mi * 16 + g * 4 + j;
          int oo = col0 + n * 16 + c;
          float val = (acc[mi][n][j] + bias[oo]) * oscale;
          int bb = rr >> 12, ss = rr & (S_LEN - 1), h2 = oo >> 6, hd = oo & 63;
          size_t idx = (((size_t)(bb * NHEAD + h2)) * S_LEN + ss) * HDIM + hd;
          out[idx] = __builtin_bit_cast(unsigned short, (_Float16)val);
        }
  } else {
    unsigned short* Ts = SMEM;   // [128][68] fp16
    __syncthreads();
    #pragma unroll
    for (int mi = 0; mi < 2; ++mi)
      #pragma unroll
      for (int n = 0; n < 4; ++n)
        #pragma unroll
        for (int j = 0; j < 4; ++j) {
          int r = w * 32 + mi * 16 + g * 4 + j;
          int o = n * 16 + c;
          Ts[r * 68 + o] = __builtin_bit_cast(unsigned short, (_Float16)(acc[mi][n][j] + bias[col0 + o]));
        }
    __syncthreads();
    int bb = row0 >> 12, sbase = row0 & (S_LEN - 1), h2 = col0 >> 6;
    int d = t >> 2, s0 = (t & 3) * 32;
    size_t obase = ((size_t)((bb * NHEAD + h2) * HDIM + d)) * S_LEN + sbase + s0;
    #pragma unroll
    for (int i = 0; i < 4; ++i) {
      u16x8 v;
      #pragma unroll
      for (int jj = 0; jj < 8; ++jj) v[jj] = Ts[(s0 + i * 8 + jj) * 68 + d];
      *(u16x8*)(out + obase + i * 8) = v;
    }
  }
}

// ---------------------------------------------------------------------------
// Final projection GEMM (1-pass, f32 out flat)
// ---------------------------------------------------------------------------
__global__ __launch_bounds__(256) void gemm_out(
    const unsigned short* __restrict__ xh, const unsigned short* __restrict__ wh,
    const float* __restrict__ bias, float* __restrict__ Y)
{
  __shared__ __align__(16) unsigned short SMEM[24576];
  unsigned short* Xh = SMEM;
  unsigned short* Wh = SMEM + 16384;

  const int t = threadIdx.x;
  const int lane = t & 63;
  const int w = t >> 6;
  const int c = lane & 15;
  const int g = lane >> 4;
  const int row0 = blockIdx.x * 128;
  const int col0 = blockIdx.y * 64;

  f32x4 acc[2][4];
  #pragma unroll
  for (int mi = 0; mi < 2; ++mi)
    #pragma unroll
    for (int n = 0; n < 4; ++n) acc[mi][n] = (f32x4){0.f, 0.f, 0.f, 0.f};

  u16x8 pxh[4], pwh[2];
  auto issue = [&](int k0) {
    #pragma unroll
    for (int i = 0; i < 4; ++i) {
      int id = i * 256 + t;
      int r = id >> 3, ch = id & 7;
      pxh[i] = *(const u16x8*)(xh + (size_t)(row0 + r) * DMODEL + k0 + ch * 8);
    }
    #pragma unroll
    for (int i = 0; i < 2; ++i) {
      int id = i * 256 + t;
      int r = id >> 3, ch = id & 7;
      pwh[i] = *(const u16x8*)(wh + (size_t)(col0 + r) * DMODEL + k0 + ch * 8);
    }
  };
  auto commit = [&]() {
    #pragma unroll
    for (int i = 0; i < 4; ++i) {
      int id = i * 256 + t;
      int r = id >> 3, ch = id & 7;
      *(u16x8*)&Xh[r * 64 + (((ch ^ r) & 7) << 3)] = pxh[i];
    }
    #pragma unroll
    for (int i = 0; i < 2; ++i) {
      int id = i * 256 + t;
      int r = id >> 3, ch = id & 7;
      *(u16x8*)&Wh[r * 64 + (((ch ^ r) & 7) << 3)] = pwh[i];
    }
  };

  issue(0);
  commit();
  __syncthreads();

  for (int k0 = 0; k0 < DMODEL; k0 += 64) {
    const bool more = (k0 + 64) < DMODEL;
    if (more) issue(k0 + 64);

    #pragma unroll
    for (int kk = 0; kk < 2; ++kk) {
      bf16x8 ah[2], bh_[4];
      #pragma unroll
      for (int mi = 0; mi < 2; ++mi)
        ah[mi] = __builtin_bit_cast(bf16x8, *(const u16x8*)&Xh[swzi(w * 32 + mi * 16 + c, (kk * 4 + g) * 8)]);
      #pragma unroll
      for (int n = 0; n < 4; ++n)
        bh_[n] = __builtin_bit_cast(bf16x8, *(const u16x8*)&Wh[swzi(n * 16 + c, (kk * 4 + g) * 8)]);
      #pragma unroll
      for (int mi = 0; mi < 2; ++mi)
        #pragma unroll
        for (int n = 0; n < 4; ++n)
          acc[mi][n] = __builtin_amdgcn_mfma_f32_16x16x32_bf16(ah[mi], bh_[n], acc[mi][n], 0, 0, 0);
    }
    __syncthreads();
    if (more) {
      commit();
      __syncthreads();
    }
  }

  #pragma unroll
  for (int mi = 0; mi < 2; ++mi)
    #pragma unroll
    for (int n = 0; n < 4; ++n)
      #pragma unroll
      for (int j = 0; j < 4; ++j) {
        int rr = row0 + w * 32 + mi * 16 + g * 4 + j;
        int oo = col0 + n * 16 + c;
        Y[(size_t)rr * DMODEL + oo] = acc[mi][n][j] + bias[oo];
      }
}

// ---------------------------------------------------------------------------
// Flash attention on 32x32x16 fp16 MFMA, swapped operands, exp2 domain.
// Mask enters as the QK^T MFMA C-operand (0 / -1e9). P-exchange via shfl_xor.
// ---------------------------------------------------------------------------
__global__ __launch_bounds__(256) void attn32(
    const unsigned short* __restrict__ qf, const unsigned short* __restrict__ kf,
    const unsigned short* __restrict__ vt, const unsigned long long* __restrict__ mbits,
    unsigned short* __restrict__ Ob)
{
  __shared__ __align__(16) unsigned short LDS[2][2][4096];   // 32 KB

  const int t = threadIdx.x;
  const int lane = t & 63;
  const int w = t >> 6;
  const int pair = w >> 1;
  const int chunk = w & 1;
  const int c31 = lane & 31;
  const int hi = lane >> 5;

  const int nwg = gridDim.x;
  const int bid = blockIdx.x;
  const int lin = (bid & 7) * (nwg >> 3) + (bid >> 3);
  const int qi = lin & 63;
  const int bh = lin >> 6;
  const int q0 = qi * 64;
  const int b = bh >> 3, h = bh & 7;
  const int qrow = q0 + pair * 32 + c31;

  const unsigned short* Qp = qf + ((size_t)bh * S_LEN + qrow) * HDIM;
  f16x8 qfr[4];
  #pragma unroll
  for (int s = 0; s < 4; ++s)
    qfr[s] = __builtin_bit_cast(f16x8, *(const u16x8*)(Qp + 16 * s + 8 * hi));

  const unsigned short* Kb = kf + (size_t)bh * S_LEN * HDIM;
  const unsigned short* Vbt = vt + (size_t)bh * HDIM * S_LEN;
  const unsigned long long* mptr = mbits + (size_t)(b * S_LEN + qrow) * NWORDS;

  // staging: wave w covers linear chunks (w*2+i)*64+lane; source pre-swizzled
  const int idx0 = (w * 2 + 0) * 64 + lane;
  const int idx1 = (w * 2 + 1) * 64 + lane;
  const int r0 = idx0 >> 3, r1 = idx1 >> 3;
  const int c0 = ((lane & 7) ^ r0) & 7, c1 = ((lane & 7) ^ r1) & 7;
  const unsigned short* nK0 = Kb + r0 * HDIM + c0 * 8;
  const unsigned short* nK1 = Kb + r1 * HDIM + c1 * 8;
  const unsigned short* nV0 = Vbt + (size_t)r0 * S_LEN + c0 * 8;
  const unsigned short* nV1 = Vbt + (size_t)r1 * S_LEN + c1 * 8;
  const int ld0 = (w * 2 + 0) * 512;
  const int ld1 = (w * 2 + 1) * 512;

  auto issue = [&](int buf) {
    gload16(nK0, &LDS[buf][0][ld0]);
    gload16(nK1, &LDS[buf][0][ld1]);
    gload16(nV0, &LDS[buf][1][ld0]);
    gload16(nV1, &LDS[buf][1][ld1]);
    nK0 += 64 * HDIM; nK1 += 64 * HDIM;
    nV0 += 64; nV1 += 64;
  };

  f32x16 oacc0, oacc1;
  #pragma unroll
  for (int r = 0; r < 16; ++r) { oacc0[r] = 0.f; oacc1[r] = 0.f; }
  float mrow = -INFINITY, lrow = 0.f;

  const int NEG = __builtin_bit_cast(int, -1.0e9f);
  unsigned long long m64 = mptr[0], m64n = 0;

  issue(0);
  __syncthreads();

  int cur = 0;
  for (int kt = 0; kt < S_LEN / 64; ++kt) {
    const bool more = kt < (S_LEN / 64 - 1);
    if (more) {
      issue(cur ^ 1);
      m64n = mptr[kt + 1];
    }
    const unsigned short* K_ = &LDS[cur][0][0];
    const unsigned short* Vt_ = &LDS[cur][1][0];

    // ---- mask -> C-operand bias (off critical path; overlaps MFMA issue) ----
    unsigned half = chunk ? (unsigned)(m64 >> 32) : (unsigned)m64;
    unsigned hsn = ~(half >> (hi * 4));   // inverted kept-bits
    f32x16 cbias;
    #pragma unroll
    for (int r = 0; r < 16; ++r) {
      int bs = (r & 3) + 8 * (r >> 2);
      cbias[r] = __builtin_bit_cast(float, bit_mask(hsn, bs) & NEG);
    }

    // ---- scores: QK^T with mask bias as C ----
    f32x16 p;
    __builtin_amdgcn_s_setprio(1);
    {
      int idx = swzi(chunk * 32 + c31, 8 * hi);
      f16x8 kfr = __builtin_bit_cast(f16x8, *(const u16x8*)&K_[idx]);
      p = __builtin_amdgcn_mfma_f32_32x32x16_f16(kfr, qfr[0], cbias, 0, 0, 0);
    }
    #pragma unroll
    for (int s = 1; s < 4; ++s) {
      int idx = swzi(chunk * 32 + c31, 16 * s + 8 * hi);
      f16x8 kfr = __builtin_bit_cast(f16x8, *(const u16x8*)&K_[idx]);
      p = __builtin_amdgcn_mfma_f32_32x32x16_f16(kfr, qfr[s], p, 0, 0, 0);
    }
    __builtin_amdgcn_s_setprio(0);

    // ---- row max (masked entries ~ -1e9) ----
    float t0 = max3f(p[0], p[1], p[2]);
    float t1 = max3f(p[3], p[4], p[5]);
    float t2 = max3f(p[6], p[7], p[8]);
    float t3 = max3f(p[9], p[10], p[11]);
    float t4 = max3f(p[12], p[13], p[14]);
    float mx = fmaxf(max3f(t0, t1, t2), max3f(t3, t4, p[15]));
    mx = xhalf_max(mx);

    float mn, scl;
    if (__all(mx <= mrow + 11.54f)) {    // defer-max
      mn = mrow;
      scl = 1.0f;
    } else {
      mn = fmaxf(mrow, mx);
      scl = fast_exp2(mrow - mn);
      mrow = mn;
      oacc0 *= scl;
      oacc1 *= scl;
    }

    // ---- exp2 (masked: exp2(~-1e9 - mn) == 0) ----
    #pragma unroll
    for (int r = 0; r < 16; ++r) p[r] = fast_exp2(p[r] - mn);

    float s0_ = (p[0] + p[1]) + (p[2] + p[3]);
    float s1_ = (p[4] + p[5]) + (p[6] + p[7]);
    float s2_ = (p[8] + p[9]) + (p[10] + p[11]);
    float s3_ = (p[12] + p[13]) + (p[14] + p[15]);
    float ps = xhalf_sum((s0_ + s1_) + (s2_ + s3_));
    lrow = lrow * scl + ps;

    // ---- P redistribution: R9/R10-verified shfl_xor keep/send/recv ----
    unsigned W[4][2];
    #pragma unroll
    for (int rq = 0; rq < 4; ++rq) {
      W[rq][0] = __builtin_bit_cast(unsigned, __builtin_amdgcn_cvt_pkrtz(p[4 * rq + 0], p[4 * rq + 1]));
      W[rq][1] = __builtin_bit_cast(unsigned, __builtin_amdgcn_cvt_pkrtz(p[4 * rq + 2], p[4 * rq + 3]));
    }
    f16x8 pf[2];
    #pragma unroll
    for (int s2 = 0; s2 < 2; ++s2) {
      unsigned keep0 = hi ? W[2 * s2 + 1][0] : W[2 * s2][0];
      unsigned keep1 = hi ? W[2 * s2 + 1][1] : W[2 * s2][1];
      unsigned send0 = hi ? W[2 * s2][0] : W[2 * s2 + 1][0];
      unsigned send1 = hi ? W[2 * s2][1] : W[2 * s2 + 1][1];
      unsigned recv0 = (unsigned)__shfl_xor((int)send0, 32, 64);
      unsigned recv1 = (unsigned)__shfl_xor((int)send1, 32, 64);
      u32x4 fw;
      fw[0] = hi ? recv0 : keep0;
      fw[1] = hi ? recv1 : keep1;
      fw[2] = hi ? keep0 : recv0;
      fw[3] = hi ? keep1 : recv1;
      pf[s2] = __builtin_bit_cast(f16x8, fw);
    }

    // ---- PV ----
    __builtin_amdgcn_s_setprio(1);
    #pragma unroll
    for (int s2 = 0; s2 < 2; ++s2) {
      int col = chunk * 32 + 16 * s2 + 8 * hi;
      f16x8 vf0 = __builtin_bit_cast(f16x8, *(const u16x8*)&Vt_[swzi(c31, col)]);
      f16x8 vf1 = __builtin_bit_cast(f16x8, *(const u16x8*)&Vt_[swzi(32 + c31, col)]);
      oacc0 = __builtin_amdgcn_mfma_f32_32x32x16_f16(vf0, pf[s2], oacc0, 0, 0, 0);
      oacc1 = __builtin_amdgcn_mfma_f32_32x32x16_f16(vf1, pf[s2], oacc1, 0, 0, 0);
    }
    __builtin_amdgcn_s_setprio(0);

    if (more) m64 = m64n;
    __syncthreads();
    cur ^= 1;
  }

  // ---- flash merge across the wave pair, via LDS ----
  float* mb = (float*)&LDS[0][0][0];   // [2 pair][2 hi][32 c31][36]
  const int mi = ((pair * 2 + hi) * 32 + c31) * 36;
  if (chunk == 1) {
    #pragma unroll
    for (int q4 = 0; q4 < 4; ++q4) {
      *(f32x4*)&mb[mi + q4 * 4]      = (f32x4){oacc0[q4 * 4], oacc0[q4 * 4 + 1], oacc0[q4 * 4 + 2], oacc0[q4 * 4 + 3]};
      *(f32x4*)&mb[mi + 16 + q4 * 4] = (f32x4){oacc1[q4 * 4], oacc1[q4 * 4 + 1], oacc1[q4 * 4 + 2], oacc1[q4 * 4 + 3]};
    }
    mb[mi + 32] = mrow;
    mb[mi + 33] = lrow;
  }
  __syncthreads();
  if (chunk == 0) {
    float m1 = mb[mi + 32], l1 = mb[mi + 33];
    float mS = fmaxf(mrow, m1);
    float f0 = fast_exp2(mrow - mS), f1 = fast_exp2(m1 - mS);
    float lS = lrow * f0 + l1 * f1;
    float inv = 1.0f / lS;
    size_t obase = ((size_t)b * S_LEN + qrow) * DMODEL + h * HDIM;
    #pragma unroll
    for (int c2 = 0; c2 < 2; ++c2) {
      #pragma unroll
      for (int rq = 0; rq < 4; ++rq) {
        u16x4 hv;
        #pragma unroll
        for (int rb = 0; rb < 4; ++rb) {
          int reg = 4 * rq + rb;
          float o0 = (c2 == 0) ? oacc0[reg] : oacc1[reg];
          float o1 = mb[mi + c2 * 16 + reg];
          hv[rb] = f2bf((o0 * f0 + o1 * f1) * inv);
        }
        *(u16x4*)(Ob + obase + 32 * c2 + 8 * rq + 4 * hi) = hv;
      }
    }
  }
}

// ---------------------------------------------------------------------------
extern "C" void kernel_launch(void* const* d_in, const int* in_sizes, int n_in,
                              void* d_out, int out_size, void* d_ws, size_t ws_size,
                              hipStream_t stream) {
  const float* query = (const float*)d_in[0];
  const float* key   = (const float*)d_in[1];
  const float* value = (const float*)d_in[2];
  const int*   mask  = (const int*)  d_in[3];
  const float* Wq = (const float*)d_in[4];
  const float* bq = (const float*)d_in[5];
  const float* Wk = (const float*)d_in[6];
  const float* bk = (const float*)d_in[7];
  const float* Wv = (const float*)d_in[8];
  const float* bv = (const float*)d_in[9];
  const float* Wo = (const float*)d_in[10];
  const float* bo = (const float*)d_in[11];
  float* out = (float*)d_out;

  const size_t PER = (size_t)2 * S_LEN * DMODEL;   // 4,194,304 elements
  const size_t WSZ = (size_t)DMODEL * DMODEL;      // 262,144

  unsigned short* p = (unsigned short*)d_ws;
  unsigned short* wbuf = p;                        // [4][2][WSZ] = 4 MB
  unsigned short* xh = p + 8 * WSZ;                // q input hi / attn out
  unsigned short* xl = xh + PER;
  unsigned short* yh = xl + PER;                   // k input hi/lo
  unsigned short* yl = yh + PER;
  unsigned short* zh = yl + PER;                   // v input hi/lo
  unsigned short* zl = zh + PER;
  unsigned short* qfb = zl + PER;                  // fp16 Q (log2e-scaled)
  unsigned short* kfb = qfb + PER;                 // fp16 K
  unsigned short* vtb = kfb + PER;                 // fp16 V^T  (total 76 MB)

  unsigned short* woh = wbuf + 3 * 2 * WSZ;

  unsigned long long* bits = (unsigned long long*)d_out;   // overwritten by gemm_out

  prep<<<dim3(2048, 5), 256, 0, stream>>>(query, key, value, Wq, Wk, Wv, Wo, mask,
                                          xh, xl, yh, yl, zh, zl, wbuf, bits);

  proj_qkv<<<dim3(2 * S_LEN / 128, DMODEL / 64, 3), 256, 0, stream>>>(
      xh, xl, yh, yl, zh, zl, wbuf, bq, bk, bv, qfb, kfb, vtb);

  attn32<<<1024, 256, 0, stream>>>(qfb, kfb, vtb, bits, xh);

  gemm_out<<<dim3(2 * S_LEN / 128, DMODEL / 64), 256, 0, stream>>>(xh, woh, bo, out);
}

// Round 14
// 251.374 us; speedup vs baseline: 1.0074x; 1.0074x over previous
//
#include <hip/hip_runtime.h>
#include <hip/hip_bf16.h>
#include <cstddef>
#include <cstdint>

// MultiHeadAttention: B=2, S=4096, D=512, H=8, HD=64
// Round 14: attn reverted to R11's verified form (post-MFMA bfi mask blend;
// cbias regressed in R13) + split-KV x2: grid 2048, each block does half the
// KV range and writes f32 partials + (m,l); merge kernel combines. Occupancy
// was grid-limited (1024 = 4 blocks/CU vs 5 LDS-allowed).

#define S_LEN 4096
#define DMODEL 512
#define NHEAD 8
#define HDIM 64
#define NWORDS (S_LEN / 64)
#define SHALF 2048
#define NTILE (SHALF / 64)

typedef __bf16 bf16x8 __attribute__((ext_vector_type(8)));
typedef _Float16 f16x8 __attribute__((ext_vector_type(8)));
typedef float f32x4 __attribute__((ext_vector_type(4)));
typedef float f32x16 __attribute__((ext_vector_type(16)));
typedef int i32x2 __attribute__((ext_vector_type(2)));
typedef unsigned int u32x4 __attribute__((ext_vector_type(4)));
typedef unsigned short u16x4 __attribute__((ext_vector_type(4)));
typedef unsigned short u16x8 __attribute__((ext_vector_type(8)));

__device__ __forceinline__ unsigned short f2bf(float x) {
  return __builtin_bit_cast(unsigned short, (__bf16)x);
}
__device__ __forceinline__ float bf2f(unsigned short h) {
  union { unsigned u; float f; } v; v.u = ((unsigned)h) << 16; return v.f;
}
__device__ __forceinline__ float fast_exp2(float x) {
#if __has_builtin(__builtin_amdgcn_exp2f)
  return __builtin_amdgcn_exp2f(x);
#else
  return __expf(x * 0.69314718056f);
#endif
}
__device__ __forceinline__ float max3f(float a, float b, float c) {
  return fmaxf(fmaxf(a, b), c);
}
__device__ __forceinline__ int bit_mask(unsigned hs, int bs) {
#if __has_builtin(__builtin_amdgcn_sbfe)
  return __builtin_amdgcn_sbfe((int)hs, bs, 1);
#else
  return ((int)(hs << (31 - bs))) >> 31;
#endif
}
// keep ? x : -1e9  (bfi)
__device__ __forceinline__ float mask_blend(float x, int msk) {
  const int NEG = __builtin_bit_cast(int, -1.0e9f);
  int xi = __builtin_bit_cast(int, x);
  return __builtin_bit_cast(float, (xi & msk) | (NEG & ~msk));
}
// permlane32_swap: SYMMETRIC REDUCTIONS ONLY (R7/R8/R12 evidence).
__device__ __forceinline__ void pl_swap(int& a, int& b) {
#if __has_builtin(__builtin_amdgcn_permlane32_swap)
  i32x2 r = __builtin_amdgcn_permlane32_swap(a, b, false, false);
  a = r[0]; b = r[1];
#else
  asm volatile("v_permlane32_swap_b32 %0, %1" : "+v"(a), "+v"(b));
#endif
}
__device__ __forceinline__ float xhalf_max(float x) {
  int a = __builtin_bit_cast(int, x), b = a;
  pl_swap(a, b);
  return fmaxf(__builtin_bit_cast(float, a), __builtin_bit_cast(float, b));
}
__device__ __forceinline__ float xhalf_sum(float x) {
  int a = __builtin_bit_cast(int, x), b = a;
  pl_swap(a, b);
  return __builtin_bit_cast(float, a) + __builtin_bit_cast(float, b);
}
__device__ __forceinline__ int swzi(int row, int col) {
  return row * 64 + ((col & 7) | ((((col >> 3) ^ row) & 7) << 3));
}
__device__ __forceinline__ void gload16(const unsigned short* g, unsigned short* lds) {
  __builtin_amdgcn_global_load_lds(
      (const __attribute__((address_space(1))) unsigned int*)g,
      (__attribute__((address_space(3))) unsigned int*)lds, 16, 0, 0);
}

// ---------------------------------------------------------------------------
// fused prep (unchanged, verified)
// ---------------------------------------------------------------------------
__global__ __launch_bounds__(256) void prep(
    const float* __restrict__ query, const float* __restrict__ key,
    const float* __restrict__ value,
    const float* __restrict__ w0, const float* __restrict__ w1,
    const float* __restrict__ w2, const float* __restrict__ w3,
    const int* __restrict__ mask,
    unsigned short* __restrict__ qh, unsigned short* __restrict__ ql,
    unsigned short* __restrict__ kh, unsigned short* __restrict__ kl,
    unsigned short* __restrict__ vh, unsigned short* __restrict__ vl,
    unsigned short* __restrict__ wbuf, unsigned long long* __restrict__ bits)
{
  const int task = blockIdx.y;
  const int tid = blockIdx.x * 256 + threadIdx.x;
  const int nthr = gridDim.x * 256;

  if (task < 3) {
    const float* x = (task == 0) ? query : (task == 1) ? key : value;
    unsigned short* h = (task == 0) ? qh : (task == 1) ? kh : vh;
    unsigned short* l = (task == 0) ? ql : (task == 1) ? kl : vl;
    const int n4 = (int)((size_t)2 * S_LEN * DMODEL / 4);
    for (int i = tid; i < n4; i += nthr) {
      float4 f = ((const float4*)x)[i];
      float ff[4] = {f.x, f.y, f.z, f.w};
      u16x4 hh, ll;
      #pragma unroll
      for (int j = 0; j < 4; ++j) {
        unsigned short hb = f2bf(ff[j]);
        hh[j] = hb;
        ll[j] = f2bf(ff[j] - bf2f(hb));
      }
      ((u16x4*)h)[i] = hh;
      ((u16x4*)l)[i] = ll;
    }
  } else if (task == 3) {
    const int per = 65536;
    for (int i = tid; i < 4 * per; i += nthr) {
      int wsel = i >> 16, idx = i & (per - 1);
      const float* src = (wsel == 0) ? w0 : (wsel == 1) ? w1 : (wsel == 2) ? w2 : w3;
      unsigned short* h = wbuf + (size_t)wsel * 2 * 262144;
      unsigned short* l = h + 262144;
      float4 f = ((const float4*)src)[idx];
      float ff[4] = {f.x, f.y, f.z, f.w};
      u16x4 hh, ll;
      #pragma unroll
      for (int j = 0; j < 4; ++j) {
        unsigned short hb = f2bf(ff[j]);
        hh[j] = hb;
        ll[j] = f2bf(ff[j] - bf2f(hb));
      }
      ((u16x4*)h)[idx] = hh;
      ((u16x4*)l)[idx] = ll;
    }
  } else {
    const int nwords = 2 * S_LEN * NWORDS;
    int gw = tid >> 6;
    int lane = threadIdx.x & 63;
    int nw = nthr >> 6;
    for (int w = gw; w < nwords; w += nw) {
      int v = mask[(size_t)w * 64 + lane];
      unsigned long long bm = __ballot(v != 0);
      if (lane == 0) bits[w] = bm;
    }
  }
}

// ---------------------------------------------------------------------------
// Fused Q/K/V projections (unchanged, verified)
// ---------------------------------------------------------------------------
__global__ __launch_bounds__(256) void proj_qkv(
    const unsigned short* __restrict__ qxh, const unsigned short* __restrict__ qxl,
    const unsigned short* __restrict__ kxh, const unsigned short* __restrict__ kxl,
    const unsigned short* __restrict__ vxh, const unsigned short* __restrict__ vxl,
    const unsigned short* __restrict__ wbuf,
    const float* __restrict__ bq, const float* __restrict__ bk, const float* __restrict__ bv,
    unsigned short* __restrict__ qout, unsigned short* __restrict__ kout,
    unsigned short* __restrict__ vout)
{
  const int mode = blockIdx.z;
  const bool tri = (mode < 2);
  const unsigned short* xh = (mode == 0) ? qxh : (mode == 1) ? kxh : vxh;
  const unsigned short* xl = (mode == 0) ? qxl : (mode == 1) ? kxl : vxl;
  const unsigned short* wh = wbuf + (size_t)mode * 2 * 262144;
  const unsigned short* wl = wh + 262144;
  const float* bias = (mode == 0) ? bq : (mode == 1) ? bk : bv;
  unsigned short* out = (mode == 0) ? qout : (mode == 1) ? kout : vout;
  const float oscale = (mode == 0) ? 1.44269504f : 1.0f;

  __shared__ __align__(16) unsigned short SMEM[24576];
  unsigned short* Xh = SMEM;
  unsigned short* Xl = SMEM + 8192;
  unsigned short* Wh = SMEM + 16384;
  unsigned short* Wl = SMEM + 20480;

  const int t = threadIdx.x;
  const int lane = t & 63;
  const int w = t >> 6;
  const int c = lane & 15;
  const int g = lane >> 4;
  const int row0 = blockIdx.x * 128;
  const int col0 = blockIdx.y * 64;

  f32x4 acc[2][4];
  #pragma unroll
  for (int mi = 0; mi < 2; ++mi)
    #pragma unroll
    for (int n = 0; n < 4; ++n) acc[mi][n] = (f32x4){0.f, 0.f, 0.f, 0.f};

  u16x8 pxh[4], pxl[4], pwh[2], pwl[2];
  auto issue = [&](int k0) {
    #pragma unroll
    for (int i = 0; i < 4; ++i) {
      int id = i * 256 + t;
      int r = id >> 3, ch = id & 7;
      size_t off = (size_t)(row0 + r) * DMODEL + k0 + ch * 8;
      pxh[i] = *(const u16x8*)(xh + off);
      if (tri) pxl[i] = *(const u16x8*)(xl + off);
    }
    #pragma unroll
    for (int i = 0; i < 2; ++i) {
      int id = i * 256 + t;
      int r = id >> 3, ch = id & 7;
      size_t off = (size_t)(col0 + r) * DMODEL + k0 + ch * 8;
      pwh[i] = *(const u16x8*)(wh + off);
      if (tri) pwl[i] = *(const u16x8*)(wl + off);
    }
  };
  auto commit = [&]() {
    #pragma unroll
    for (int i = 0; i < 4; ++i) {
      int id = i * 256 + t;
      int r = id >> 3, ch = id & 7;
      int dst = r * 64 + (((ch ^ r) & 7) << 3);
      *(u16x8*)&Xh[dst] = pxh[i];
      if (tri) *(u16x8*)&Xl[dst] = pxl[i];
    }
    #pragma unroll
    for (int i = 0; i < 2; ++i) {
      int id = i * 256 + t;
      int r = id >> 3, ch = id & 7;
      int dst = r * 64 + (((ch ^ r) & 7) << 3);
      *(u16x8*)&Wh[dst] = pwh[i];
      if (tri) *(u16x8*)&Wl[dst] = pwl[i];
    }
  };

  issue(0);
  commit();
  __syncthreads();

  for (int k0 = 0; k0 < DMODEL; k0 += 64) {
    const bool more = (k0 + 64) < DMODEL;
    if (more) issue(k0 + 64);

    #pragma unroll
    for (int kk = 0; kk < 2; ++kk) {
      bf16x8 ah[2], al[2], bh_[4], bl_[4];
      #pragma unroll
      for (int mi = 0; mi < 2; ++mi) {
        int r = w * 32 + mi * 16 + c;
        ah[mi] = __builtin_bit_cast(bf16x8, *(const u16x8*)&Xh[swzi(r, (kk * 4 + g) * 8)]);
        if (tri) al[mi] = __builtin_bit_cast(bf16x8, *(const u16x8*)&Xl[swzi(r, (kk * 4 + g) * 8)]);
      }
      #pragma unroll
      for (int n = 0; n < 4; ++n) {
        int r = n * 16 + c;
        bh_[n] = __builtin_bit_cast(bf16x8, *(const u16x8*)&Wh[swzi(r, (kk * 4 + g) * 8)]);
        if (tri) bl_[n] = __builtin_bit_cast(bf16x8, *(const u16x8*)&Wl[swzi(r, (kk * 4 + g) * 8)]);
      }
      #pragma unroll
      for (int mi = 0; mi < 2; ++mi)
        #pragma unroll
        for (int n = 0; n < 4; ++n) {
          acc[mi][n] = __builtin_amdgcn_mfma_f32_16x16x32_bf16(ah[mi], bh_[n], acc[mi][n], 0, 0, 0);
          if (tri) {
            acc[mi][n] = __builtin_amdgcn_mfma_f32_16x16x32_bf16(al[mi], bh_[n], acc[mi][n], 0, 0, 0);
            acc[mi][n] = __builtin_amdgcn_mfma_f32_16x16x32_bf16(ah[mi], bl_[n], acc[mi][n], 0, 0, 0);
          }
        }
    }
    __syncthreads();
    if (more) {
      commit();
      __syncthreads();
    }
  }

  if (mode < 2) {
    #pragma unroll
    for (int mi = 0; mi < 2; ++mi)
      #pragma unroll
      for (int n = 0; n < 4; ++n)
        #pragma unroll
        for (int j = 0; j < 4; ++j) {
          int rr = row0 + w * 32 + mi * 16 + g * 4 + j;
          int oo = col0 + n * 16 + c;
          float val = (acc[mi][n][j] + bias[oo]) * oscale;
          int bb = rr >> 12, ss = rr & (S_LEN - 1), h2 = oo >> 6, hd = oo & 63;
          size_t idx = (((size_t)(bb * NHEAD + h2)) * S_LEN + ss) * HDIM + hd;
          out[idx] = __builtin_bit_cast(unsigned short, (_Float16)val);
        }
  } else {
    unsigned short* Ts = SMEM;   // [128][68] fp16
    __syncthreads();
    #pragma unroll
    for (int mi = 0; mi < 2; ++mi)
      #pragma unroll
      for (int n = 0; n < 4; ++n)
        #pragma unroll
        for (int j = 0; j < 4; ++j) {
          int r = w * 32 + mi * 16 + g * 4 + j;
          int o = n * 16 + c;
          Ts[r * 68 + o] = __builtin_bit_cast(unsigned short, (_Float16)(acc[mi][n][j] + bias[col0 + o]));
        }
    __syncthreads();
    int bb = row0 >> 12, sbase = row0 & (S_LEN - 1), h2 = col0 >> 6;
    int d = t >> 2, s0 = (t & 3) * 32;
    size_t obase = ((size_t)((bb * NHEAD + h2) * HDIM + d)) * S_LEN + sbase + s0;
    #pragma unroll
    for (int i = 0; i < 4; ++i) {
      u16x8 v;
      #pragma unroll
      for (int jj = 0; jj < 8; ++jj) v[jj] = Ts[(s0 + i * 8 + jj) * 68 + d];
      *(u16x8*)(out + obase + i * 8) = v;
    }
  }
}

// ---------------------------------------------------------------------------
// Final projection GEMM (unchanged, verified)
// ---------------------------------------------------------------------------
__global__ __launch_bounds__(256) void gemm_out(
    const unsigned short* __restrict__ xh, const unsigned short* __restrict__ wh,
    const float* __restrict__ bias, float* __restrict__ Y)
{
  __shared__ __align__(16) unsigned short SMEM[24576];
  unsigned short* Xh = SMEM;
  unsigned short* Wh = SMEM + 16384;

  const int t = threadIdx.x;
  const int lane = t & 63;
  const int w = t >> 6;
  const int c = lane & 15;
  const int g = lane >> 4;
  const int row0 = blockIdx.x * 128;
  const int col0 = blockIdx.y * 64;

  f32x4 acc[2][4];
  #pragma unroll
  for (int mi = 0; mi < 2; ++mi)
    #pragma unroll
    for (int n = 0; n < 4; ++n) acc[mi][n] = (f32x4){0.f, 0.f, 0.f, 0.f};

  u16x8 pxh[4], pwh[2];
  auto issue = [&](int k0) {
    #pragma unroll
    for (int i = 0; i < 4; ++i) {
      int id = i * 256 + t;
      int r = id >> 3, ch = id & 7;
      pxh[i] = *(const u16x8*)(xh + (size_t)(row0 + r) * DMODEL + k0 + ch * 8);
    }
    #pragma unroll
    for (int i = 0; i < 2; ++i) {
      int id = i * 256 + t;
      int r = id >> 3, ch = id & 7;
      pwh[i] = *(const u16x8*)(wh + (size_t)(col0 + r) * DMODEL + k0 + ch * 8);
    }
  };
  auto commit = [&]() {
    #pragma unroll
    for (int i = 0; i < 4; ++i) {
      int id = i * 256 + t;
      int r = id >> 3, ch = id & 7;
      *(u16x8*)&Xh[r * 64 + (((ch ^ r) & 7) << 3)] = pxh[i];
    }
    #pragma unroll
    for (int i = 0; i < 2; ++i) {
      int id = i * 256 + t;
      int r = id >> 3, ch = id & 7;
      *(u16x8*)&Wh[r * 64 + (((ch ^ r) & 7) << 3)] = pwh[i];
    }
  };

  issue(0);
  commit();
  __syncthreads();

  for (int k0 = 0; k0 < DMODEL; k0 += 64) {
    const bool more = (k0 + 64) < DMODEL;
    if (more) issue(k0 + 64);

    #pragma unroll
    for (int kk = 0; kk < 2; ++kk) {
      bf16x8 ah[2], bh_[4];
      #pragma unroll
      for (int mi = 0; mi < 2; ++mi)
        ah[mi] = __builtin_bit_cast(bf16x8, *(const u16x8*)&Xh[swzi(w * 32 + mi * 16 + c, (kk * 4 + g) * 8)]);
      #pragma unroll
      for (int n = 0; n < 4; ++n)
        bh_[n] = __builtin_bit_cast(bf16x8, *(const u16x8*)&Wh[swzi(n * 16 + c, (kk * 4 + g) * 8)]);
      #pragma unroll
      for (int mi = 0; mi < 2; ++mi)
        #pragma unroll
        for (int n = 0; n < 4; ++n)
          acc[mi][n] = __builtin_amdgcn_mfma_f32_16x16x32_bf16(ah[mi], bh_[n], acc[mi][n], 0, 0, 0);
    }
    __syncthreads();
    if (more) {
      commit();
      __syncthreads();
    }
  }

  #pragma unroll
  for (int mi = 0; mi < 2; ++mi)
    #pragma unroll
    for (int n = 0; n < 4; ++n)
      #pragma unroll
      for (int j = 0; j < 4; ++j) {
        int rr = row0 + w * 32 + mi * 16 + g * 4 + j;
        int oo = col0 + n * 16 + c;
        Y[(size_t)rr * DMODEL + oo] = acc[mi][n][j] + bias[oo];
      }
}

// ---------------------------------------------------------------------------
// Flash attention, split-KV x2. Block = (qi, bh, half); each block covers 2048
// KV positions and writes f32 partials + (m,l). Core = R11-verified math.
// ---------------------------------------------------------------------------
__global__ __launch_bounds__(256) void attn32(
    const unsigned short* __restrict__ qf, const unsigned short* __restrict__ kf,
    const unsigned short* __restrict__ vt, const unsigned long long* __restrict__ mbits,
    float* __restrict__ part, float* __restrict__ mlb)
{
  __shared__ __align__(16) unsigned short LDS[2][2][4096];   // 32 KB

  const int t = threadIdx.x;
  const int lane = t & 63;
  const int w = t >> 6;
  const int pair = w >> 1;
  const int chunk = w & 1;
  const int c31 = lane & 31;
  const int hi = lane >> 5;

  // XCD swizzle over 2048 blocks (2048%8==0); half is the slowest bit so
  // consecutive lin share (qi,bh) locality.
  const int nwg = gridDim.x;
  const int bid = blockIdx.x;
  const int lin = (bid & 7) * (nwg >> 3) + (bid >> 3);
  const int qi = lin & 63;
  const int bh = (lin >> 6) & 15;
  const int half = lin >> 10;
  const int q0 = qi * 64;
  const int b = bh >> 3, h = bh & 7;
  const int qrow = q0 + pair * 32 + c31;
  const size_t PERF32 = (size_t)2 * S_LEN * DMODEL;

  const unsigned short* Qp = qf + ((size_t)bh * S_LEN + qrow) * HDIM;
  f16x8 qfr[4];
  #pragma unroll
  for (int s = 0; s < 4; ++s)
    qfr[s] = __builtin_bit_cast(f16x8, *(const u16x8*)(Qp + 16 * s + 8 * hi));

  const unsigned short* Kb = kf + (size_t)bh * S_LEN * HDIM;
  const unsigned short* Vbt = vt + (size_t)bh * HDIM * S_LEN;
  const unsigned long long* mptr =
      mbits + (size_t)(b * S_LEN + qrow) * NWORDS + half * NTILE;

  // staging: wave w covers linear chunks (w*2+i)*64+lane; source pre-swizzled
  const int idx0 = (w * 2 + 0) * 64 + lane;
  const int idx1 = (w * 2 + 1) * 64 + lane;
  const int r0 = idx0 >> 3, r1 = idx1 >> 3;
  const int c0 = ((lane & 7) ^ r0) & 7, c1 = ((lane & 7) ^ r1) & 7;
  const unsigned short* nK0 = Kb + (size_t)(half * SHALF + r0) * HDIM + c0 * 8;
  const unsigned short* nK1 = Kb + (size_t)(half * SHALF + r1) * HDIM + c1 * 8;
  const unsigned short* nV0 = Vbt + (size_t)r0 * S_LEN + half * SHALF + c0 * 8;
  const unsigned short* nV1 = Vbt + (size_t)r1 * S_LEN + half * SHALF + c1 * 8;
  const int ld0 = (w * 2 + 0) * 512;
  const int ld1 = (w * 2 + 1) * 512;

  auto issue = [&](int buf) {
    gload16(nK0, &LDS[buf][0][ld0]);
    gload16(nK1, &LDS[buf][0][ld1]);
    gload16(nV0, &LDS[buf][1][ld0]);
    gload16(nV1, &LDS[buf][1][ld1]);
    nK0 += 64 * HDIM; nK1 += 64 * HDIM;
    nV0 += 64; nV1 += 64;
  };

  f32x16 oacc0, oacc1;
  #pragma unroll
  for (int r = 0; r < 16; ++r) { oacc0[r] = 0.f; oacc1[r] = 0.f; }
  const f32x16 fzero = oacc0;
  float mrow = -INFINITY, lrow = 0.f;

  unsigned long long m64 = mptr[0], m64n = 0;

  issue(0);
  __syncthreads();

  int cur = 0;
  for (int kt = 0; kt < NTILE; ++kt) {
    const bool more = kt < (NTILE - 1);
    if (more) {
      issue(cur ^ 1);
      m64n = mptr[kt + 1];
    }
    const unsigned short* K_ = &LDS[cur][0][0];
    const unsigned short* Vt_ = &LDS[cur][1][0];

    // ---- scores (single fp16 pass) ----
    f32x16 p;
    __builtin_amdgcn_s_setprio(1);
    {
      int idx = swzi(chunk * 32 + c31, 8 * hi);
      f16x8 kfr = __builtin_bit_cast(f16x8, *(const u16x8*)&K_[idx]);
      p = __builtin_amdgcn_mfma_f32_32x32x16_f16(kfr, qfr[0], fzero, 0, 0, 0);
    }
    #pragma unroll
    for (int s = 1; s < 4; ++s) {
      int idx = swzi(chunk * 32 + c31, 16 * s + 8 * hi);
      f16x8 kfr = __builtin_bit_cast(f16x8, *(const u16x8*)&K_[idx]);
      p = __builtin_amdgcn_mfma_f32_32x32x16_f16(kfr, qfr[s], p, 0, 0, 0);
    }
    __builtin_amdgcn_s_setprio(0);

    // ---- mask BEFORE max (bfi blend to -1e9) — R10/R11-verified ----
    unsigned halfw = chunk ? (unsigned)(m64 >> 32) : (unsigned)m64;
    unsigned hs = halfw >> (hi * 4);
    #pragma unroll
    for (int r = 0; r < 16; ++r) {
      int bs = (r & 3) + 8 * (r >> 2);
      p[r] = mask_blend(p[r], bit_mask(hs, bs));
    }

    // ---- masked row max ----
    float t0 = max3f(p[0], p[1], p[2]);
    float t1 = max3f(p[3], p[4], p[5]);
    float t2 = max3f(p[6], p[7], p[8]);
    float t3 = max3f(p[9], p[10], p[11]);
    float t4 = max3f(p[12], p[13], p[14]);
    float mx = fmaxf(max3f(t0, t1, t2), max3f(t3, t4, p[15]));
    mx = xhalf_max(mx);

    float mn, scl;
    if (__all(mx <= mrow + 11.54f)) {    // defer-max
      mn = mrow;
      scl = 1.0f;
    } else {
      mn = fmaxf(mrow, mx);
      scl = fast_exp2(mrow - mn);
      mrow = mn;
      oacc0 *= scl;
      oacc1 *= scl;
    }

    // ---- exp2 ----
    #pragma unroll
    for (int r = 0; r < 16; ++r) p[r] = fast_exp2(p[r] - mn);

    float s0_ = (p[0] + p[1]) + (p[2] + p[3]);
    float s1_ = (p[4] + p[5]) + (p[6] + p[7]);
    float s2_ = (p[8] + p[9]) + (p[10] + p[11]);
    float s3_ = (p[12] + p[13]) + (p[14] + p[15]);
    float ps = xhalf_sum((s0_ + s1_) + (s2_ + s3_));
    lrow = lrow * scl + ps;

    // ---- P redistribution: verified shfl_xor keep/send/recv ----
    unsigned W[4][2];
    #pragma unroll
    for (int rq = 0; rq < 4; ++rq) {
      W[rq][0] = __builtin_bit_cast(unsigned, __builtin_amdgcn_cvt_pkrtz(p[4 * rq + 0], p[4 * rq + 1]));
      W[rq][1] = __builtin_bit_cast(unsigned, __builtin_amdgcn_cvt_pkrtz(p[4 * rq + 2], p[4 * rq + 3]));
    }
    f16x8 pf[2];
    #pragma unroll
    for (int s2 = 0; s2 < 2; ++s2) {
      unsigned keep0 = hi ? W[2 * s2 + 1][0] : W[2 * s2][0];
      unsigned keep1 = hi ? W[2 * s2 + 1][1] : W[2 * s2][1];
      unsigned send0 = hi ? W[2 * s2][0] : W[2 * s2 + 1][0];
      unsigned send1 = hi ? W[2 * s2][1] : W[2 * s2 + 1][1];
      unsigned recv0 = (unsigned)__shfl_xor((int)send0, 32, 64);
      unsigned recv1 = (unsigned)__shfl_xor((int)send1, 32, 64);
      u32x4 fw;
      fw[0] = hi ? recv0 : keep0;
      fw[1] = hi ? recv1 : keep1;
      fw[2] = hi ? keep0 : recv0;
      fw[3] = hi ? keep1 : recv1;
      pf[s2] = __builtin_bit_cast(f16x8, fw);
    }

    // ---- PV ----
    __builtin_amdgcn_s_setprio(1);
    #pragma unroll
    for (int s2 = 0; s2 < 2; ++s2) {
      int col = chunk * 32 + 16 * s2 + 8 * hi;
      f16x8 vf0 = __builtin_bit_cast(f16x8, *(const u16x8*)&Vt_[swzi(c31, col)]);
      f16x8 vf1 = __builtin_bit_cast(f16x8, *(const u16x8*)&Vt_[swzi(32 + c31, col)]);
      oacc0 = __builtin_amdgcn_mfma_f32_32x32x16_f16(vf0, pf[s2], oacc0, 0, 0, 0);
      oacc1 = __builtin_amdgcn_mfma_f32_32x32x16_f16(vf1, pf[s2], oacc1, 0, 0, 0);
    }
    __builtin_amdgcn_s_setprio(0);

    if (more) m64 = m64n;
    __syncthreads();
    cur ^= 1;
  }

  // ---- in-pair flash merge, then write f32 partials + (m,l) ----
  float* mb = (float*)&LDS[0][0][0];   // [2 pair][2 hi][32 c31][36]
  const int mi = ((pair * 2 + hi) * 32 + c31) * 36;
  if (chunk == 1) {
    #pragma unroll
    for (int q4 = 0; q4 < 4; ++q4) {
      *(f32x4*)&mb[mi + q4 * 4]      = (f32x4){oacc0[q4 * 4], oacc0[q4 * 4 + 1], oacc0[q4 * 4 + 2], oacc0[q4 * 4 + 3]};
      *(f32x4*)&mb[mi + 16 + q4 * 4] = (f32x4){oacc1[q4 * 4], oacc1[q4 * 4 + 1], oacc1[q4 * 4 + 2], oacc1[q4 * 4 + 3]};
    }
    mb[mi + 32] = mrow;
    mb[mi + 33] = lrow;
  }
  __syncthreads();
  if (chunk == 0) {
    float m1 = mb[mi + 32], l1 = mb[mi + 33];
    float mS = fmaxf(mrow, m1);
    float f0 = fast_exp2(mrow - mS), f1 = fast_exp2(m1 - mS);
    float lS = lrow * f0 + l1 * f1;
    float* po = part + (size_t)half * PERF32 + ((size_t)b * S_LEN + qrow) * DMODEL + h * HDIM;
    #pragma unroll
    for (int c2 = 0; c2 < 2; ++c2) {
      #pragma unroll
      for (int rq = 0; rq < 4; ++rq) {
        f32x4 v;
        #pragma unroll
        for (int rb = 0; rb < 4; ++rb) {
          int reg = 4 * rq + rb;
          float o0 = (c2 == 0) ? oacc0[reg] : oacc1[reg];
          float o1 = mb[mi + c2 * 16 + reg];
          v[rb] = o0 * f0 + o1 * f1;
        }
        *(f32x4*)(po + 32 * c2 + 8 * rq + 4 * hi) = v;
      }
    }
    if (hi == 0) {
      size_t mli = (((size_t)half * 16 + bh) * S_LEN + qrow) * 2;
      mlb[mli] = mS;
      mlb[mli + 1] = lS;
    }
  }
}

// ---------------------------------------------------------------------------
// Merge the two KV halves: O = (p0*f0 + p1*f1) / (l0*f0 + l1*f1), bf16 out.
// ---------------------------------------------------------------------------
__global__ __launch_bounds__(256) void merge_halves(
    const float* __restrict__ part, const float* __restrict__ mlb,
    unsigned short* __restrict__ Ob)
{
  const size_t PERF32 = (size_t)2 * S_LEN * DMODEL;
  int idx4 = blockIdx.x * 256 + threadIdx.x;   // over PERF32/4 = 1,048,576
  int row = idx4 >> 7;                          // token row 0..8191
  int col4 = idx4 & 127;
  int h = col4 >> 4;
  int b = row >> 12;
  int s = row & (S_LEN - 1);
  int bh = b * NHEAD + h;

  size_t mli = ((size_t)bh * S_LEN + s) * 2;
  float m0 = mlb[mli], l0 = mlb[mli + 1];
  float m1 = mlb[(size_t)16 * S_LEN * 2 + mli], l1 = mlb[(size_t)16 * S_LEN * 2 + mli + 1];
  float mf = fmaxf(m0, m1);
  float f0 = fast_exp2(m0 - mf), f1 = fast_exp2(m1 - mf);
  float inv = 1.0f / (l0 * f0 + l1 * f1);

  f32x4 p0 = *(const f32x4*)(part + (size_t)idx4 * 4);
  f32x4 p1 = *(const f32x4*)(part + PERF32 + (size_t)idx4 * 4);
  u16x4 o;
  #pragma unroll
  for (int j = 0; j < 4; ++j) o[j] = f2bf((p0[j] * f0 + p1[j] * f1) * inv);
  *(u16x4*)(Ob + (size_t)idx4 * 4) = o;
}

// ---------------------------------------------------------------------------
extern "C" void kernel_launch(void* const* d_in, const int* in_sizes, int n_in,
                              void* d_out, int out_size, void* d_ws, size_t ws_size,
                              hipStream_t stream) {
  const float* query = (const float*)d_in[0];
  const float* key   = (const float*)d_in[1];
  const float* value = (const float*)d_in[2];
  const int*   mask  = (const int*)  d_in[3];
  const float* Wq = (const float*)d_in[4];
  const float* bq = (const float*)d_in[5];
  const float* Wk = (const float*)d_in[6];
  const float* bk = (const float*)d_in[7];
  const float* Wv = (const float*)d_in[8];
  const float* bv = (const float*)d_in[9];
  const float* Wo = (const float*)d_in[10];
  const float* bo = (const float*)d_in[11];
  float* out = (float*)d_out;

  const size_t PER = (size_t)2 * S_LEN * DMODEL;   // 4,194,304 elements
  const size_t WSZ = (size_t)DMODEL * DMODEL;      // 262,144

  unsigned short* p = (unsigned short*)d_ws;
  unsigned short* wbuf = p;                        // [4][2][WSZ] = 4 MB
  unsigned short* xh = p + 8 * WSZ;                // q input hi / attn out (merge dst)
  unsigned short* xl = xh + PER;                   // after proj: partial0 (f32, 16MB: xl+yh)
  unsigned short* yh = xl + PER;
  unsigned short* yl = yh + PER;                   // partial1 (f32, 16MB: yl+zh)
  unsigned short* zh = yl + PER;
  unsigned short* zl = zh + PER;                   // ml buffer (1MB of 8MB)
  unsigned short* qfb = zl + PER;                  // fp16 Q (log2e-scaled)
  unsigned short* kfb = qfb + PER;                 // fp16 K
  unsigned short* vtb = kfb + PER;                 // fp16 V^T

  unsigned short* woh = wbuf + 3 * 2 * WSZ;

  unsigned long long* bits = (unsigned long long*)d_out;   // overwritten by gemm_out

  prep<<<dim3(2048, 5), 256, 0, stream>>>(query, key, value, Wq, Wk, Wv, Wo, mask,
                                          xh, xl, yh, yl, zh, zl, wbuf, bits);

  proj_qkv<<<dim3(2 * S_LEN / 128, DMODEL / 64, 3), 256, 0, stream>>>(
      xh, xl, yh, yl, zh, zl, wbuf, bq, bk, bv, qfb, kfb, vtb);

  float* part = (float*)xl;   // 32 MB: [2][B*S][D] f32 (xl..zh, free after proj)
  float* mlb  = (float*)zl;   // [2][16][S][2] f32 = 1 MB

  attn32<<<2048, 256, 0, stream>>>(qfb, kfb, vtb, bits, part, mlb);

  merge_halves<<<(int)(PER / 4 / 256), 256, 0, stream>>>(part, mlb, xh);

  gemm_out<<<dim3(2 * S_LEN / 128, DMODEL / 64), 256, 0, stream>>>(xh, woh, bo, out);
}

// Round 15
// 245.204 us; speedup vs baseline: 1.0328x; 1.0252x over previous
//
#include <hip/hip_runtime.h>
#include <hip/hip_bf16.h>
#include <cstddef>
#include <cstdint>

// MultiHeadAttention: B=2, S=4096, D=512, H=8, HD=64
// Round 15 (final): exact revert to the R11 session-best configuration
// (246.3 us measured). Split-KV (R14) removed: merge overhead (~11us) exceeded
// the attn gain (~4us). Attention is VALU-issue-bound (VALUBusy+MfmaUtil ~88%);
// remaining levers (cbias-in-C, permlane exchange, split-KV) all measured
// negative or broken on this hardware.

#define S_LEN 4096
#define DMODEL 512
#define NHEAD 8
#define HDIM 64
#define NWORDS (S_LEN / 64)

typedef __bf16 bf16x8 __attribute__((ext_vector_type(8)));
typedef _Float16 f16x8 __attribute__((ext_vector_type(8)));
typedef float f32x4 __attribute__((ext_vector_type(4)));
typedef float f32x16 __attribute__((ext_vector_type(16)));
typedef int i32x2 __attribute__((ext_vector_type(2)));
typedef unsigned int u32x4 __attribute__((ext_vector_type(4)));
typedef unsigned short u16x4 __attribute__((ext_vector_type(4)));
typedef unsigned short u16x8 __attribute__((ext_vector_type(8)));

__device__ __forceinline__ unsigned short f2bf(float x) {
  return __builtin_bit_cast(unsigned short, (__bf16)x);
}
__device__ __forceinline__ float bf2f(unsigned short h) {
  union { unsigned u; float f; } v; v.u = ((unsigned)h) << 16; return v.f;
}
__device__ __forceinline__ float fast_exp2(float x) {
#if __has_builtin(__builtin_amdgcn_exp2f)
  return __builtin_amdgcn_exp2f(x);
#else
  return __expf(x * 0.69314718056f);
#endif
}
__device__ __forceinline__ float max3f(float a, float b, float c) {
  return fmaxf(fmaxf(a, b), c);
}
__device__ __forceinline__ int bit_mask(unsigned hs, int bs) {
#if __has_builtin(__builtin_amdgcn_sbfe)
  return __builtin_amdgcn_sbfe((int)hs, bs, 1);
#else
  return ((int)(hs << (31 - bs))) >> 31;
#endif
}
// keep ? x : -1e9  (bfi)
__device__ __forceinline__ float mask_blend(float x, int msk) {
  const int NEG = __builtin_bit_cast(int, -1.0e9f);
  int xi = __builtin_bit_cast(int, x);
  return __builtin_bit_cast(float, (xi & msk) | (NEG & ~msk));
}
// permlane32_swap: SYMMETRIC REDUCTIONS ONLY (R7/R8/R12 evidence — asymmetric
// exchanges through this op are broken under every assumed semantic).
__device__ __forceinline__ void pl_swap(int& a, int& b) {
#if __has_builtin(__builtin_amdgcn_permlane32_swap)
  i32x2 r = __builtin_amdgcn_permlane32_swap(a, b, false, false);
  a = r[0]; b = r[1];
#else
  asm volatile("v_permlane32_swap_b32 %0, %1" : "+v"(a), "+v"(b));
#endif
}
__device__ __forceinline__ float xhalf_max(float x) {
  int a = __builtin_bit_cast(int, x), b = a;
  pl_swap(a, b);
  return fmaxf(__builtin_bit_cast(float, a), __builtin_bit_cast(float, b));
}
__device__ __forceinline__ float xhalf_sum(float x) {
  int a = __builtin_bit_cast(int, x), b = a;
  pl_swap(a, b);
  return __builtin_bit_cast(float, a) + __builtin_bit_cast(float, b);
}
// swizzled ushort index into a [*][64] 16-bit tile
__device__ __forceinline__ int swzi(int row, int col) {
  return row * 64 + ((col & 7) | ((((col >> 3) ^ row) & 7) << 3));
}
// async global->LDS, 16B per lane; LDS dest = lds + lane*16B (wave-uniform base)
__device__ __forceinline__ void gload16(const unsigned short* g, unsigned short* lds) {
  __builtin_amdgcn_global_load_lds(
      (const __attribute__((address_space(1))) unsigned int*)g,
      (__attribute__((address_space(3))) unsigned int*)lds, 16, 0, 0);
}

// ---------------------------------------------------------------------------
// fused prep: hi/lo conversions for q,k,v + 4 weights, mask packing. grid (2048,5)
// ---------------------------------------------------------------------------
__global__ __launch_bounds__(256) void prep(
    const float* __restrict__ query, const float* __restrict__ key,
    const float* __restrict__ value,
    const float* __restrict__ w0, const float* __restrict__ w1,
    const float* __restrict__ w2, const float* __restrict__ w3,
    const int* __restrict__ mask,
    unsigned short* __restrict__ qh, unsigned short* __restrict__ ql,
    unsigned short* __restrict__ kh, unsigned short* __restrict__ kl,
    unsigned short* __restrict__ vh, unsigned short* __restrict__ vl,
    unsigned short* __restrict__ wbuf, unsigned long long* __restrict__ bits)
{
  const int task = blockIdx.y;
  const int tid = blockIdx.x * 256 + threadIdx.x;
  const int nthr = gridDim.x * 256;

  if (task < 3) {
    const float* x = (task == 0) ? query : (task == 1) ? key : value;
    unsigned short* h = (task == 0) ? qh : (task == 1) ? kh : vh;
    unsigned short* l = (task == 0) ? ql : (task == 1) ? kl : vl;
    const int n4 = (int)((size_t)2 * S_LEN * DMODEL / 4);
    for (int i = tid; i < n4; i += nthr) {
      float4 f = ((const float4*)x)[i];
      float ff[4] = {f.x, f.y, f.z, f.w};
      u16x4 hh, ll;
      #pragma unroll
      for (int j = 0; j < 4; ++j) {
        unsigned short hb = f2bf(ff[j]);
        hh[j] = hb;
        ll[j] = f2bf(ff[j] - bf2f(hb));
      }
      ((u16x4*)h)[i] = hh;
      ((u16x4*)l)[i] = ll;
    }
  } else if (task == 3) {
    const int per = 65536;
    for (int i = tid; i < 4 * per; i += nthr) {
      int wsel = i >> 16, idx = i & (per - 1);
      const float* src = (wsel == 0) ? w0 : (wsel == 1) ? w1 : (wsel == 2) ? w2 : w3;
      unsigned short* h = wbuf + (size_t)wsel * 2 * 262144;
      unsigned short* l = h + 262144;
      float4 f = ((const float4*)src)[idx];
      float ff[4] = {f.x, f.y, f.z, f.w};
      u16x4 hh, ll;
      #pragma unroll
      for (int j = 0; j < 4; ++j) {
        unsigned short hb = f2bf(ff[j]);
        hh[j] = hb;
        ll[j] = f2bf(ff[j] - bf2f(hb));
      }
      ((u16x4*)h)[idx] = hh;
      ((u16x4*)l)[idx] = ll;
    }
  } else {
    const int nwords = 2 * S_LEN * NWORDS;
    int gw = tid >> 6;
    int lane = threadIdx.x & 63;
    int nw = nthr >> 6;
    for (int w = gw; w < nwords; w += nw) {
      int v = mask[(size_t)w * 64 + lane];
      unsigned long long bm = __ballot(v != 0);
      if (lane == 0) bits[w] = bm;
    }
  }
}

// ---------------------------------------------------------------------------
// Fused Q/K/V projections in one launch. blockIdx.z = mode:
//  0: Q (3-pass hi/lo, out fp16 head-split, *log2e)
//  1: K (3-pass hi/lo, out fp16 head-split)
//  2: V (1-pass, out fp16 transposed [B,H,HD,S])
// ---------------------------------------------------------------------------
__global__ __launch_bounds__(256) void proj_qkv(
    const unsigned short* __restrict__ qxh, const unsigned short* __restrict__ qxl,
    const unsigned short* __restrict__ kxh, const unsigned short* __restrict__ kxl,
    const unsigned short* __restrict__ vxh, const unsigned short* __restrict__ vxl,
    const unsigned short* __restrict__ wbuf,
    const float* __restrict__ bq, const float* __restrict__ bk, const float* __restrict__ bv,
    unsigned short* __restrict__ qout, unsigned short* __restrict__ kout,
    unsigned short* __restrict__ vout)
{
  const int mode = blockIdx.z;
  const bool tri = (mode < 2);
  const unsigned short* xh = (mode == 0) ? qxh : (mode == 1) ? kxh : vxh;
  const unsigned short* xl = (mode == 0) ? qxl : (mode == 1) ? kxl : vxl;
  const unsigned short* wh = wbuf + (size_t)mode * 2 * 262144;
  const unsigned short* wl = wh + 262144;
  const float* bias = (mode == 0) ? bq : (mode == 1) ? bk : bv;
  unsigned short* out = (mode == 0) ? qout : (mode == 1) ? kout : vout;
  const float oscale = (mode == 0) ? 1.44269504f : 1.0f;

  __shared__ __align__(16) unsigned short SMEM[24576];
  unsigned short* Xh = SMEM;
  unsigned short* Xl = SMEM + 8192;
  unsigned short* Wh = SMEM + 16384;
  unsigned short* Wl = SMEM + 20480;

  const int t = threadIdx.x;
  const int lane = t & 63;
  const int w = t >> 6;
  const int c = lane & 15;
  const int g = lane >> 4;
  const int row0 = blockIdx.x * 128;
  const int col0 = blockIdx.y * 64;

  f32x4 acc[2][4];
  #pragma unroll
  for (int mi = 0; mi < 2; ++mi)
    #pragma unroll
    for (int n = 0; n < 4; ++n) acc[mi][n] = (f32x4){0.f, 0.f, 0.f, 0.f};

  u16x8 pxh[4], pxl[4], pwh[2], pwl[2];
  auto issue = [&](int k0) {
    #pragma unroll
    for (int i = 0; i < 4; ++i) {
      int id = i * 256 + t;
      int r = id >> 3, ch = id & 7;
      size_t off = (size_t)(row0 + r) * DMODEL + k0 + ch * 8;
      pxh[i] = *(const u16x8*)(xh + off);
      if (tri) pxl[i] = *(const u16x8*)(xl + off);
    }
    #pragma unroll
    for (int i = 0; i < 2; ++i) {
      int id = i * 256 + t;
      int r = id >> 3, ch = id & 7;
      size_t off = (size_t)(col0 + r) * DMODEL + k0 + ch * 8;
      pwh[i] = *(const u16x8*)(wh + off);
      if (tri) pwl[i] = *(const u16x8*)(wl + off);
    }
  };
  auto commit = [&]() {
    #pragma unroll
    for (int i = 0; i < 4; ++i) {
      int id = i * 256 + t;
      int r = id >> 3, ch = id & 7;
      int dst = r * 64 + (((ch ^ r) & 7) << 3);
      *(u16x8*)&Xh[dst] = pxh[i];
      if (tri) *(u16x8*)&Xl[dst] = pxl[i];
    }
    #pragma unroll
    for (int i = 0; i < 2; ++i) {
      int id = i * 256 + t;
      int r = id >> 3, ch = id & 7;
      int dst = r * 64 + (((ch ^ r) & 7) << 3);
      *(u16x8*)&Wh[dst] = pwh[i];
      if (tri) *(u16x8*)&Wl[dst] = pwl[i];
    }
  };

  issue(0);
  commit();
  __syncthreads();

  for (int k0 = 0; k0 < DMODEL; k0 += 64) {
    const bool more = (k0 + 64) < DMODEL;
    if (more) issue(k0 + 64);

    #pragma unroll
    for (int kk = 0; kk < 2; ++kk) {
      bf16x8 ah[2], al[2], bh_[4], bl_[4];
      #pragma unroll
      for (int mi = 0; mi < 2; ++mi) {
        int r = w * 32 + mi * 16 + c;
        ah[mi] = __builtin_bit_cast(bf16x8, *(const u16x8*)&Xh[swzi(r, (kk * 4 + g) * 8)]);
        if (tri) al[mi] = __builtin_bit_cast(bf16x8, *(const u16x8*)&Xl[swzi(r, (kk * 4 + g) * 8)]);
      }
      #pragma unroll
      for (int n = 0; n < 4; ++n) {
        int r = n * 16 + c;
        bh_[n] = __builtin_bit_cast(bf16x8, *(const u16x8*)&Wh[swzi(r, (kk * 4 + g) * 8)]);
        if (tri) bl_[n] = __builtin_bit_cast(bf16x8, *(const u16x8*)&Wl[swzi(r, (kk * 4 + g) * 8)]);
      }
      #pragma unroll
      for (int mi = 0; mi < 2; ++mi)
        #pragma unroll
        for (int n = 0; n < 4; ++n) {
          acc[mi][n] = __builtin_amdgcn_mfma_f32_16x16x32_bf16(ah[mi], bh_[n], acc[mi][n], 0, 0, 0);
          if (tri) {
            acc[mi][n] = __builtin_amdgcn_mfma_f32_16x16x32_bf16(al[mi], bh_[n], acc[mi][n], 0, 0, 0);
            acc[mi][n] = __builtin_amdgcn_mfma_f32_16x16x32_bf16(ah[mi], bl_[n], acc[mi][n], 0, 0, 0);
          }
        }
    }
    __syncthreads();
    if (more) {
      commit();
      __syncthreads();
    }
  }

  if (mode < 2) {
    #pragma unroll
    for (int mi = 0; mi < 2; ++mi)
      #pragma unroll
      for (int n = 0; n < 4; ++n)
        #pragma unroll
        for (int j = 0; j < 4; ++j) {
          int rr = row0 + w * 32 + mi * 16 + g * 4 + j;
          int oo = col0 + n * 16 + c;
          float val = (acc[mi][n][j] + bias[oo]) * oscale;
          int bb = rr >> 12, ss = rr & (S_LEN - 1), h2 = oo >> 6, hd = oo & 63;
          size_t idx = (((size_t)(bb * NHEAD + h2)) * S_LEN + ss) * HDIM + hd;
          out[idx] = __builtin_bit_cast(unsigned short, (_Float16)val);
        }
  } else {
    unsigned short* Ts = SMEM;   // [128][68] fp16
    __syncthreads();
    #pragma unroll
    for (int mi = 0; mi < 2; ++mi)
      #pragma unroll
      for (int n = 0; n < 4; ++n)
        #pragma unroll
        for (int j = 0; j < 4; ++j) {
          int r = w * 32 + mi * 16 + g * 4 + j;
          int o = n * 16 + c;
          Ts[r * 68 + o] = __builtin_bit_cast(unsigned short, (_Float16)(acc[mi][n][j] + bias[col0 + o]));
        }
    __syncthreads();
    int bb = row0 >> 12, sbase = row0 & (S_LEN - 1), h2 = col0 >> 6;
    int d = t >> 2, s0 = (t & 3) * 32;
    size_t obase = ((size_t)((bb * NHEAD + h2) * HDIM + d)) * S_LEN + sbase + s0;
    #pragma unroll
    for (int i = 0; i < 4; ++i) {
      u16x8 v;
      #pragma unroll
      for (int jj = 0; jj < 8; ++jj) v[jj] = Ts[(s0 + i * 8 + jj) * 68 + d];
      *(u16x8*)(out + obase + i * 8) = v;
    }
  }
}

// ---------------------------------------------------------------------------
// Final projection GEMM (1-pass, f32 out flat)
// ---------------------------------------------------------------------------
__global__ __launch_bounds__(256) void gemm_out(
    const unsigned short* __restrict__ xh, const unsigned short* __restrict__ wh,
    const float* __restrict__ bias, float* __restrict__ Y)
{
  __shared__ __align__(16) unsigned short SMEM[24576];
  unsigned short* Xh = SMEM;
  unsigned short* Wh = SMEM + 16384;

  const int t = threadIdx.x;
  const int lane = t & 63;
  const int w = t >> 6;
  const int c = lane & 15;
  const int g = lane >> 4;
  const int row0 = blockIdx.x * 128;
  const int col0 = blockIdx.y * 64;

  f32x4 acc[2][4];
  #pragma unroll
  for (int mi = 0; mi < 2; ++mi)
    #pragma unroll
    for (int n = 0; n < 4; ++n) acc[mi][n] = (f32x4){0.f, 0.f, 0.f, 0.f};

  u16x8 pxh[4], pwh[2];
  auto issue = [&](int k0) {
    #pragma unroll
    for (int i = 0; i < 4; ++i) {
      int id = i * 256 + t;
      int r = id >> 3, ch = id & 7;
      pxh[i] = *(const u16x8*)(xh + (size_t)(row0 + r) * DMODEL + k0 + ch * 8);
    }
    #pragma unroll
    for (int i = 0; i < 2; ++i) {
      int id = i * 256 + t;
      int r = id >> 3, ch = id & 7;
      pwh[i] = *(const u16x8*)(wh + (size_t)(col0 + r) * DMODEL + k0 + ch * 8);
    }
  };
  auto commit = [&]() {
    #pragma unroll
    for (int i = 0; i < 4; ++i) {
      int id = i * 256 + t;
      int r = id >> 3, ch = id & 7;
      *(u16x8*)&Xh[r * 64 + (((ch ^ r) & 7) << 3)] = pxh[i];
    }
    #pragma unroll
    for (int i = 0; i < 2; ++i) {
      int id = i * 256 + t;
      int r = id >> 3, ch = id & 7;
      *(u16x8*)&Wh[r * 64 + (((ch ^ r) & 7) << 3)] = pwh[i];
    }
  };

  issue(0);
  commit();
  __syncthreads();

  for (int k0 = 0; k0 < DMODEL; k0 += 64) {
    const bool more = (k0 + 64) < DMODEL;
    if (more) issue(k0 + 64);

    #pragma unroll
    for (int kk = 0; kk < 2; ++kk) {
      bf16x8 ah[2], bh_[4];
      #pragma unroll
      for (int mi = 0; mi < 2; ++mi)
        ah[mi] = __builtin_bit_cast(bf16x8, *(const u16x8*)&Xh[swzi(w * 32 + mi * 16 + c, (kk * 4 + g) * 8)]);
      #pragma unroll
      for (int n = 0; n < 4; ++n)
        bh_[n] = __builtin_bit_cast(bf16x8, *(const u16x8*)&Wh[swzi(n * 16 + c, (kk * 4 + g) * 8)]);
      #pragma unroll
      for (int mi = 0; mi < 2; ++mi)
        #pragma unroll
        for (int n = 0; n < 4; ++n)
          acc[mi][n] = __builtin_amdgcn_mfma_f32_16x16x32_bf16(ah[mi], bh_[n], acc[mi][n], 0, 0, 0);
    }
    __syncthreads();
    if (more) {
      commit();
      __syncthreads();
    }
  }

  #pragma unroll
  for (int mi = 0; mi < 2; ++mi)
    #pragma unroll
    for (int n = 0; n < 4; ++n)
      #pragma unroll
      for (int j = 0; j < 4; ++j) {
        int rr = row0 + w * 32 + mi * 16 + g * 4 + j;
        int oo = col0 + n * 16 + c;
        Y[(size_t)rr * DMODEL + oo] = acc[mi][n][j] + bias[oo];
      }
}

// ---------------------------------------------------------------------------
// Flash attention on 32x32x16 fp16 MFMA, swapped operands, exp2 domain.
// Staging via global_load_lds: linear LDS dest, inverse-swizzled global source.
// ---------------------------------------------------------------------------
__global__ __launch_bounds__(256) void attn32(
    const unsigned short* __restrict__ qf, const unsigned short* __restrict__ kf,
    const unsigned short* __restrict__ vt, const unsigned long long* __restrict__ mbits,
    unsigned short* __restrict__ Ob)
{
  __shared__ __align__(16) unsigned short LDS[2][2][4096];   // 32 KB

  const int t = threadIdx.x;
  const int lane = t & 63;
  const int w = t >> 6;
  const int pair = w >> 1;
  const int chunk = w & 1;
  const int c31 = lane & 31;
  const int hi = lane >> 5;

  const int nwg = gridDim.x;
  const int bid = blockIdx.x;
  const int lin = (bid & 7) * (nwg >> 3) + (bid >> 3);
  const int qi = lin & 63;
  const int bh = lin >> 6;
  const int q0 = qi * 64;
  const int b = bh >> 3, h = bh & 7;
  const int qrow = q0 + pair * 32 + c31;

  const unsigned short* Qp = qf + ((size_t)bh * S_LEN + qrow) * HDIM;
  f16x8 qfr[4];
  #pragma unroll
  for (int s = 0; s < 4; ++s)
    qfr[s] = __builtin_bit_cast(f16x8, *(const u16x8*)(Qp + 16 * s + 8 * hi));

  const unsigned short* Kb = kf + (size_t)bh * S_LEN * HDIM;
  const unsigned short* Vbt = vt + (size_t)bh * HDIM * S_LEN;
  const unsigned long long* mptr = mbits + (size_t)(b * S_LEN + qrow) * NWORDS;

  // staging slots: wave w covers linear chunk idx = (w*2+i)*64 + lane, i=0,1.
  // linear LDS pos idx holds source chunk (lane&7)^row (swizzle involution).
  const int idx0 = (w * 2 + 0) * 64 + lane;
  const int idx1 = (w * 2 + 1) * 64 + lane;
  const int r0 = idx0 >> 3, r1 = idx1 >> 3;
  const int c0 = ((lane & 7) ^ r0) & 7, c1 = ((lane & 7) ^ r1) & 7;
  const unsigned short* nK0 = Kb + r0 * HDIM + c0 * 8;
  const unsigned short* nK1 = Kb + r1 * HDIM + c1 * 8;
  const unsigned short* nV0 = Vbt + (size_t)r0 * S_LEN + c0 * 8;
  const unsigned short* nV1 = Vbt + (size_t)r1 * S_LEN + c1 * 8;
  const int ld0 = (w * 2 + 0) * 512;   // short offset of this wave's 1KB region
  const int ld1 = (w * 2 + 1) * 512;

  auto issue = [&](int buf) {
    gload16(nK0, &LDS[buf][0][ld0]);
    gload16(nK1, &LDS[buf][0][ld1]);
    gload16(nV0, &LDS[buf][1][ld0]);
    gload16(nV1, &LDS[buf][1][ld1]);
    nK0 += 64 * HDIM; nK1 += 64 * HDIM;   // next KV tile: +64 rows
    nV0 += 64; nV1 += 64;                 // next KV tile: +64 cols
  };

  f32x16 oacc0, oacc1;
  #pragma unroll
  for (int r = 0; r < 16; ++r) { oacc0[r] = 0.f; oacc1[r] = 0.f; }
  const f32x16 fzero = oacc0;
  float mrow = -INFINITY, lrow = 0.f;

  unsigned long long m64 = mptr[0], m64n = 0;

  issue(0);
  __syncthreads();   // barrier drains vmcnt -> LDS[0] ready

  int cur = 0;
  for (int kt = 0; kt < S_LEN / 64; ++kt) {
    const bool more = kt < (S_LEN / 64 - 1);
    if (more) {
      issue(cur ^ 1);
      m64n = mptr[kt + 1];
    }
    const unsigned short* K_ = &LDS[cur][0][0];
    const unsigned short* Vt_ = &LDS[cur][1][0];

    // ---- scores (single fp16 pass) ----
    f32x16 p;
    __builtin_amdgcn_s_setprio(1);
    {
      int idx = swzi(chunk * 32 + c31, 8 * hi);
      f16x8 kfr = __builtin_bit_cast(f16x8, *(const u16x8*)&K_[idx]);
      p = __builtin_amdgcn_mfma_f32_32x32x16_f16(kfr, qfr[0], fzero, 0, 0, 0);
    }
    #pragma unroll
    for (int s = 1; s < 4; ++s) {
      int idx = swzi(chunk * 32 + c31, 16 * s + 8 * hi);
      f16x8 kfr = __builtin_bit_cast(f16x8, *(const u16x8*)&K_[idx]);
      p = __builtin_amdgcn_mfma_f32_32x32x16_f16(kfr, qfr[s], p, 0, 0, 0);
    }
    __builtin_amdgcn_s_setprio(0);

    // ---- mask BEFORE max (bfi blend to -1e9) ----
    unsigned half = chunk ? (unsigned)(m64 >> 32) : (unsigned)m64;
    unsigned hs = half >> (hi * 4);
    #pragma unroll
    for (int r = 0; r < 16; ++r) {
      int bs = (r & 3) + 8 * (r >> 2);
      p[r] = mask_blend(p[r], bit_mask(hs, bs));
    }

    // ---- masked row max ----
    float t0 = max3f(p[0], p[1], p[2]);
    float t1 = max3f(p[3], p[4], p[5]);
    float t2 = max3f(p[6], p[7], p[8]);
    float t3 = max3f(p[9], p[10], p[11]);
    float t4 = max3f(p[12], p[13], p[14]);
    float mx = fmaxf(max3f(t0, t1, t2), max3f(t3, t4, p[15]));
    mx = xhalf_max(mx);

    float mn, scl;
    if (__all(mx <= mrow + 11.54f)) {    // defer-max
      mn = mrow;
      scl = 1.0f;
    } else {
      mn = fmaxf(mrow, mx);
      scl = fast_exp2(mrow - mn);
      mrow = mn;
      oacc0 *= scl;
      oacc1 *= scl;
    }

    // ---- exp2 ----
    #pragma unroll
    for (int r = 0; r < 16; ++r) p[r] = fast_exp2(p[r] - mn);

    float s0_ = (p[0] + p[1]) + (p[2] + p[3]);
    float s1_ = (p[4] + p[5]) + (p[6] + p[7]);
    float s2_ = (p[8] + p[9]) + (p[10] + p[11]);
    float s3_ = (p[12] + p[13]) + (p[14] + p[15]);
    float ps = xhalf_sum((s0_ + s1_) + (s2_ + s3_));
    lrow = lrow * scl + ps;

    // ---- P redistribution (verified shfl_xor keep/send/recv) ----
    unsigned W[4][2];
    #pragma unroll
    for (int rq = 0; rq < 4; ++rq) {
      W[rq][0] = __builtin_bit_cast(unsigned, __builtin_amdgcn_cvt_pkrtz(p[4 * rq + 0], p[4 * rq + 1]));
      W[rq][1] = __builtin_bit_cast(unsigned, __builtin_amdgcn_cvt_pkrtz(p[4 * rq + 2], p[4 * rq + 3]));
    }
    f16x8 pf[2];
    #pragma unroll
    for (int s2 = 0; s2 < 2; ++s2) {
      unsigned keep0 = hi ? W[2 * s2 + 1][0] : W[2 * s2][0];
      unsigned keep1 = hi ? W[2 * s2 + 1][1] : W[2 * s2][1];
      unsigned send0 = hi ? W[2 * s2][0] : W[2 * s2 + 1][0];
      unsigned send1 = hi ? W[2 * s2][1] : W[2 * s2 + 1][1];
      unsigned recv0 = (unsigned)__shfl_xor((int)send0, 32, 64);
      unsigned recv1 = (unsigned)__shfl_xor((int)send1, 32, 64);
      u32x4 fw;
      fw[0] = hi ? recv0 : keep0;
      fw[1] = hi ? recv1 : keep1;
      fw[2] = hi ? keep0 : recv0;
      fw[3] = hi ? keep1 : recv1;
      pf[s2] = __builtin_bit_cast(f16x8, fw);
    }

    // ---- PV ----
    __builtin_amdgcn_s_setprio(1);
    #pragma unroll
    for (int s2 = 0; s2 < 2; ++s2) {
      int col = chunk * 32 + 16 * s2 + 8 * hi;
      f16x8 vf0 = __builtin_bit_cast(f16x8, *(const u16x8*)&Vt_[swzi(c31, col)]);
      f16x8 vf1 = __builtin_bit_cast(f16x8, *(const u16x8*)&Vt_[swzi(32 + c31, col)]);
      oacc0 = __builtin_amdgcn_mfma_f32_32x32x16_f16(vf0, pf[s2], oacc0, 0, 0, 0);
      oacc1 = __builtin_amdgcn_mfma_f32_32x32x16_f16(vf1, pf[s2], oacc1, 0, 0, 0);
    }
    __builtin_amdgcn_s_setprio(0);

    if (more) m64 = m64n;
    __syncthreads();   // drains gload_lds (vmcnt) + protects LDS[cur] reuse
    cur ^= 1;
  }

  // ---- flash merge across the wave pair, via LDS ----
  float* mb = (float*)&LDS[0][0][0];   // [2 pair][2 hi][32 c31][36]
  const int mi = ((pair * 2 + hi) * 32 + c31) * 36;
  if (chunk == 1) {
    #pragma unroll
    for (int q4 = 0; q4 < 4; ++q4) {
      *(f32x4*)&mb[mi + q4 * 4]      = (f32x4){oacc0[q4 * 4], oacc0[q4 * 4 + 1], oacc0[q4 * 4 + 2], oacc0[q4 * 4 + 3]};
      *(f32x4*)&mb[mi + 16 + q4 * 4] = (f32x4){oacc1[q4 * 4], oacc1[q4 * 4 + 1], oacc1[q4 * 4 + 2], oacc1[q4 * 4 + 3]};
    }
    mb[mi + 32] = mrow;
    mb[mi + 33] = lrow;
  }
  __syncthreads();
  if (chunk == 0) {
    float m1 = mb[mi + 32], l1 = mb[mi + 33];
    float mS = fmaxf(mrow, m1);
    float f0 = fast_exp2(mrow - mS), f1 = fast_exp2(m1 - mS);
    float lS = lrow * f0 + l1 * f1;
    float inv = 1.0f / lS;
    size_t obase = ((size_t)b * S_LEN + qrow) * DMODEL + h * HDIM;
    #pragma unroll
    for (int c2 = 0; c2 < 2; ++c2) {
      #pragma unroll
      for (int rq = 0; rq < 4; ++rq) {
        u16x4 hv;
        #pragma unroll
        for (int rb = 0; rb < 4; ++rb) {
          int reg = 4 * rq + rb;
          float o0 = (c2 == 0) ? oacc0[reg] : oacc1[reg];
          float o1 = mb[mi + c2 * 16 + reg];
          hv[rb] = f2bf((o0 * f0 + o1 * f1) * inv);
        }
        *(u16x4*)(Ob + obase + 32 * c2 + 8 * rq + 4 * hi) = hv;
      }
    }
  }
}

// ---------------------------------------------------------------------------
extern "C" void kernel_launch(void* const* d_in, const int* in_sizes, int n_in,
                              void* d_out, int out_size, void* d_ws, size_t ws_size,
                              hipStream_t stream) {
  const float* query = (const float*)d_in[0];
  const float* key   = (const float*)d_in[1];
  const float* value = (const float*)d_in[2];
  const int*   mask  = (const int*)  d_in[3];
  const float* Wq = (const float*)d_in[4];
  const float* bq = (const float*)d_in[5];
  const float* Wk = (const float*)d_in[6];
  const float* bk = (const float*)d_in[7];
  const float* Wv = (const float*)d_in[8];
  const float* bv = (const float*)d_in[9];
  const float* Wo = (const float*)d_in[10];
  const float* bo = (const float*)d_in[11];
  float* out = (float*)d_out;

  const size_t PER = (size_t)2 * S_LEN * DMODEL;   // 4,194,304 elements
  const size_t WSZ = (size_t)DMODEL * DMODEL;      // 262,144

  unsigned short* p = (unsigned short*)d_ws;
  unsigned short* wbuf = p;                        // [4][2][WSZ] = 4 MB
  unsigned short* xh = p + 8 * WSZ;                // q input hi / attn out
  unsigned short* xl = xh + PER;
  unsigned short* yh = xl + PER;                   // k input hi/lo
  unsigned short* yl = yh + PER;
  unsigned short* zh = yl + PER;                   // v input hi/lo
  unsigned short* zl = zh + PER;
  unsigned short* qfb = zl + PER;                  // fp16 Q (log2e-scaled)
  unsigned short* kfb = qfb + PER;                 // fp16 K
  unsigned short* vtb = kfb + PER;                 // fp16 V^T  (total 76 MB)

  unsigned short* woh = wbuf + 3 * 2 * WSZ;

  unsigned long long* bits = (unsigned long long*)d_out;   // overwritten by gemm_out

  prep<<<dim3(2048, 5), 256, 0, stream>>>(query, key, value, Wq, Wk, Wv, Wo, mask,
                                          xh, xl, yh, yl, zh, zl, wbuf, bits);

  proj_qkv<<<dim3(2 * S_LEN / 128, DMODEL / 64, 3), 256, 0, stream>>>(
      xh, xl, yh, yl, zh, zl, wbuf, bq, bk, bv, qfb, kfb, vtb);

  attn32<<<1024, 256, 0, stream>>>(qfb, kfb, vtb, bits, xh);

  gemm_out<<<dim3(2 * S_LEN / 128, DMODEL / 64), 256, 0, stream>>>(xh, woh, bo, out);
}